// Round 6
// baseline (425.194 us; speedup 1.0000x reference)
//
#include <hip/hip_runtime.h>
#include <hip/hip_bf16.h>

// PropNet on MI355X — fp32 in/out, bf16 MFMA compute, 6 fused launches.
// B=4, N=1024, E=8192, NF_IN=32, H=128, NF_OUT=3, pstep=2 (fixed).
//
// Launches (6), each boundary a true grid-wide dependency:
//   K1 k_prep      : weight->bf16 fragment prep + agg zero + one-hot extract
//   K2 k_enc       : edge encoder (blocks 0..2047) + node encoder (2048..2303)
//   K3 k_eprop     : prop edge layer (K=384) + fused atomic scatter into agg
//   K4 k_nprop     : prop node layer (K=256, residual) + agg re-zero
//   K5 k_eprop     : step 2
//   K6 k_nprop_pred: prop node layer 2 (nef2 stays in LDS) + predictor + head
// GEMM: 16x16x32 bf16 MFMA, 1-wave blocks, 16 rows x 128 cols per wave.
// Inter-layer activations in bf16 LDS slabs (stride 136 u16 -> <=2-way alias).
//
// R5 bug fixed here: k_prep's segment search must advance the prefix
// unconditionally, otherwise segments following a larger one (ep, K=384)
// leak threads into later segments and leave f_epW[32768:] unwritten.

typedef unsigned short u16;
typedef __attribute__((ext_vector_type(8))) __bf16 bf16x8;
typedef __attribute__((ext_vector_type(4))) float f32x4;

#define N_    1024
#define BN    4096      // B*N
#define BE    32768     // B*E
#define LOG_E 13
#define H_    128
#define LSTR  136       // LDS slab stride (u16)
#define TOTW  208896    // sum(K_i)*128 = 1632*128

__device__ __forceinline__ u16 f2bf(float f) {
    __bf16 h = (__bf16)f;
    return __builtin_bit_cast(u16, h);
}
__device__ __forceinline__ float bf2f(u16 u) {
    return __uint_as_float(((unsigned)u) << 16);
}

__device__ __forceinline__ bf16x8 a_from_f32(const float* p) {
    float4 f0 = *(const float4*)p;
    float4 f1 = *(const float4*)(p + 4);
    bf16x8 a;
    a[0] = (__bf16)f0.x; a[1] = (__bf16)f0.y; a[2] = (__bf16)f0.z; a[3] = (__bf16)f0.w;
    a[4] = (__bf16)f1.x; a[5] = (__bf16)f1.y; a[6] = (__bf16)f1.z; a[7] = (__bf16)f1.w;
    return a;
}
__device__ __forceinline__ bf16x8 a_from_slab(const u16* s, int m, int quad, int c) {
    return *(const bf16x8*)(s + m * LSTR + c * 32 + quad * 8);
}

__device__ __forceinline__ void mm8(const u16* __restrict__ Wf, int c, bf16x8 a,
                                    f32x4* acc, int lane) {
    const u16* wp = Wf + ((size_t)c * 8) * 64 * 8;
    #pragma unroll
    for (int nt = 0; nt < 8; ++nt) {
        bf16x8 bw = *(const bf16x8*)(wp + (size_t)(nt * 64 + lane) * 8);
        acc[nt] = __builtin_amdgcn_mfma_f32_16x16x32_bf16(a, bw, acc[nt], 0, 0, 0);
    }
}
__device__ __forceinline__ void zacc(f32x4* acc) {
    #pragma unroll
    for (int t = 0; t < 8; ++t) acc[t] = (f32x4){0.f, 0.f, 0.f, 0.f};
}
// bias+ReLU epilogue into bf16 LDS slab (C-layout: row=quad*4+i, col=nt*16+m)
__device__ __forceinline__ void epi_slab(u16* s, const f32x4* acc,
                                         const float* __restrict__ bias,
                                         int quad, int m) {
    #pragma unroll
    for (int nt = 0; nt < 8; ++nt) {
        float bv = bias[nt * 16 + m];
        #pragma unroll
        for (int i = 0; i < 4; ++i)
            s[(quad * 4 + i) * LSTR + nt * 16 + m] = f2bf(fmaxf(acc[nt][i] + bv, 0.f));
    }
}

// ---------------------------------------------------------------------------
// K1: weight fragment prep + agg zero + one-hot index extract.
// 2048 blocks x 256 threads (8192 waves).
// ---------------------------------------------------------------------------
struct WDesc { const float* src; u16* dst; };
struct WPack { WDesc d[10]; };

__global__ __launch_bounds__(256) void k_prep(WPack P, float* __restrict__ agg,
                                              const float* __restrict__ Rr,
                                              const float* __restrict__ Rs,
                                              int* __restrict__ recv,
                                              int* __restrict__ send) {
    const int Kt[10] = {32, 128, 128, 64, 128, 128, 384, 256, 256, 128};
    int tg = blockIdx.x * 256 + threadIdx.x;

    // weight permutation (TOTW elements, one pass)
    if (tg < TOTW) {
        // prefix scan: pref advances unconditionally (R5 bugfix)
        int pref = 0, base = 0, mi = 0;
        #pragma unroll
        for (int q = 0; q < 10; ++q) {
            int nb = pref + Kt[q] * 128;
            if (tg >= nb) { base = nb; mi = q + 1; }
            pref = nb;
        }
        int i = tg - base;
        int j = i & 7, ln = (i >> 3) & 63, nt = (i >> 9) & 7, c = i >> 12;
        int k = c * 32 + (ln >> 4) * 8 + j;
        int n = nt * 16 + (ln & 15);
        P.d[mi].dst[i] = f2bf(P.d[mi].src[k * 128 + n]);
    }
    // agg zero (BN*H_/4 = 131072 float4)
    if (tg < BN * H_ / 4)
        ((float4*)agg)[tg] = make_float4(0.f, 0.f, 0.f, 0.f);

    // extract: 8 rows per wave
    int wid = blockIdx.x * 4 + (threadIdx.x >> 6);
    int lane = threadIdx.x & 63;
    for (int r2 = 0; r2 < 8; ++r2) {
        int gidx = wid * 8 + r2;
        const float* src; int* dst;
        if (gidx < BE) { src = Rr + (size_t)gidx * N_;        dst = recv + gidx; }
        else           { src = Rs + (size_t)(gidx - BE) * N_; dst = send + (gidx - BE); }
        int idx = 0;
        bool done = false;
        #pragma unroll
        for (int it = 0; it < 4; ++it) {
            if (!done) {
                int bp = it * 256 + lane * 4;
                float4 v = *(const float4*)(src + bp);
                int found = -1;
                if      (v.x != 0.f) found = bp;
                else if (v.y != 0.f) found = bp + 1;
                else if (v.z != 0.f) found = bp + 2;
                else if (v.w != 0.f) found = bp + 3;
                unsigned long long msk = __ballot(found >= 0);
                if (msk) {
                    idx = __shfl(found, __ffsll((long long)msk) - 1, 64);
                    done = true;
                }
            }
        }
        if (lane == 0) *dst = idx;
    }
}

// ---------------------------------------------------------------------------
// K2: encoders. Blocks 0..2047: edge tile; 2048..2303: node tile.
// ---------------------------------------------------------------------------
__global__ __launch_bounds__(64) void k_enc(
    const float* __restrict__ x,
    const int* __restrict__ recv, const int* __restrict__ send,
    const u16* __restrict__ neW0, const float* __restrict__ neb0,
    const u16* __restrict__ neW1, const float* __restrict__ neb1,
    const u16* __restrict__ neW2, const float* __restrict__ neb2,
    const u16* __restrict__ eeW0, const float* __restrict__ eeb0,
    const u16* __restrict__ eeW1, const float* __restrict__ eeb1,
    const u16* __restrict__ eeW2, const float* __restrict__ eeb2,
    float* __restrict__ nenc, u16* __restrict__ eenc)
{
    __shared__ u16 sl0[16 * LSTR];
    __shared__ u16 sl1[16 * LSTR];
    int lane = threadIdx.x, m = lane & 15, quad = lane >> 4;
    f32x4 acc[8];

    if (blockIdx.x < 2048) {            // ---- edge encoder tile
        int row16 = blockIdx.x * 16;
        int e = row16 + m, b = e >> LOG_E;
        long rr = (long)b * N_ + recv[e];
        long rs = (long)b * N_ + send[e];
        zacc(acc);
        mm8(eeW0, 0, a_from_f32(x + rr * 32 + quad * 8), acc, lane);
        mm8(eeW0, 1, a_from_f32(x + rs * 32 + quad * 8), acc, lane);
        epi_slab(sl0, acc, eeb0, quad, m);
        zacc(acc);
        #pragma unroll
        for (int c = 0; c < 4; ++c) mm8(eeW1, c, a_from_slab(sl0, m, quad, c), acc, lane);
        epi_slab(sl1, acc, eeb1, quad, m);
        zacc(acc);
        #pragma unroll
        for (int c = 0; c < 4; ++c) mm8(eeW2, c, a_from_slab(sl1, m, quad, c), acc, lane);
        epi_slab(sl0, acc, eeb2, quad, m);
        // coalesced bf16 store of the 16x128 tile
        #pragma unroll
        for (int t = 0; t < 16; ++t) {
            int flat = t * 64 + lane;
            int r = flat >> 6, col2 = (flat & 63) * 2;
            unsigned v = (unsigned)sl0[r * LSTR + col2] |
                         ((unsigned)sl0[r * LSTR + col2 + 1] << 16);
            *(unsigned*)(eenc + (size_t)(row16 + r) * H_ + col2) = v;
        }
    } else {                            // ---- node encoder tile
        int row16 = (blockIdx.x - 2048) * 16;
        zacc(acc);
        mm8(neW0, 0, a_from_f32(x + (size_t)(row16 + m) * 32 + quad * 8), acc, lane);
        epi_slab(sl0, acc, neb0, quad, m);
        zacc(acc);
        #pragma unroll
        for (int c = 0; c < 4; ++c) mm8(neW1, c, a_from_slab(sl0, m, quad, c), acc, lane);
        epi_slab(sl1, acc, neb1, quad, m);
        zacc(acc);
        #pragma unroll
        for (int c = 0; c < 4; ++c) mm8(neW2, c, a_from_slab(sl1, m, quad, c), acc, lane);
        #pragma unroll
        for (int nt = 0; nt < 8; ++nt) {     // fp32 store straight from acc
            float bv = neb2[nt * 16 + m];
            #pragma unroll
            for (int i = 0; i < 4; ++i)
                nenc[(size_t)(row16 + quad * 4 + i) * H_ + nt * 16 + m] =
                    fmaxf(acc[nt][i] + bv, 0.f);
        }
    }
}

// ---------------------------------------------------------------------------
// K3/K5: prop edge layer: relu(concat(eenc, eff[recv], eff[send]) @ epW + epb)
// fused scatter-add into fp32 agg.
// ---------------------------------------------------------------------------
__global__ __launch_bounds__(64) void k_eprop(
    const u16* __restrict__ eenc, const float* __restrict__ eff,
    const int* __restrict__ recv, const int* __restrict__ send,
    const u16* __restrict__ Wf, const float* __restrict__ bias,
    float* __restrict__ agg)
{
    int lane = threadIdx.x, m = lane & 15, quad = lane >> 4;
    int row16 = blockIdx.x * 16;
    int e = row16 + m, b = e >> LOG_E;
    long rr = (long)b * N_ + recv[e];
    long rs = (long)b * N_ + send[e];
    f32x4 acc[8];
    zacc(acc);

    #pragma unroll
    for (int c = 0; c < 4; ++c)
        mm8(Wf, c, *(const bf16x8*)(eenc + (size_t)e * H_ + c * 32 + quad * 8), acc, lane);
    #pragma unroll
    for (int c = 0; c < 4; ++c)
        mm8(Wf, 4 + c, a_from_f32(eff + rr * H_ + c * 32 + quad * 8), acc, lane);
    #pragma unroll
    for (int c = 0; c < 4; ++c)
        mm8(Wf, 8 + c, a_from_f32(eff + rs * H_ + c * 32 + quad * 8), acc, lane);

    size_t tgt[4];
    #pragma unroll
    for (int i = 0; i < 4; ++i) {
        int r = row16 + quad * 4 + i;
        tgt[i] = ((size_t)(r >> LOG_E) * N_ + recv[r]) * H_;
    }
    #pragma unroll
    for (int nt = 0; nt < 8; ++nt) {
        int col = nt * 16 + m;
        float bv = bias[col];
        #pragma unroll
        for (int i = 0; i < 4; ++i)
            atomicAdd(agg + tgt[i] + col, fmaxf(acc[nt][i] + bv, 0.f));
    }
}

// ---------------------------------------------------------------------------
// K4: prop node layer: relu(concat(nenc, agg) @ npW + npb + eff) -> nout,
// then re-zero agg rows for the next step.
// ---------------------------------------------------------------------------
__global__ __launch_bounds__(64) void k_nprop(
    const float* __restrict__ nenc, float* __restrict__ agg,
    const float* __restrict__ eff,
    const u16* __restrict__ Wf, const float* __restrict__ bias,
    float* __restrict__ nout)
{
    int lane = threadIdx.x, m = lane & 15, quad = lane >> 4;
    int row16 = blockIdx.x * 16, row = row16 + m;
    f32x4 acc[8];
    zacc(acc);
    #pragma unroll
    for (int c = 0; c < 4; ++c)
        mm8(Wf, c, a_from_f32(nenc + (size_t)row * H_ + c * 32 + quad * 8), acc, lane);
    #pragma unroll
    for (int c = 0; c < 4; ++c)
        mm8(Wf, 4 + c, a_from_f32(agg + (size_t)row * H_ + c * 32 + quad * 8), acc, lane);
    #pragma unroll
    for (int nt = 0; nt < 8; ++nt) {
        int col = nt * 16 + m;
        float bv = bias[col];
        #pragma unroll
        for (int i = 0; i < 4; ++i) {
            int r = row16 + quad * 4 + i;
            float v = fmaxf(acc[nt][i] + bv + eff[(size_t)r * H_ + col], 0.f);
            nout[(size_t)r * H_ + col] = v;
            agg[(size_t)r * H_ + col] = 0.f;   // re-zero for next prop step
        }
    }
}

// ---------------------------------------------------------------------------
// K6: second prop node layer (nef2 kept in LDS) + predictor + head.
// ---------------------------------------------------------------------------
__global__ __launch_bounds__(64) void k_nprop_pred(
    const float* __restrict__ nenc, const float* __restrict__ agg,
    const float* __restrict__ eff,
    const u16* __restrict__ Wnp, const float* __restrict__ npb,
    const u16* __restrict__ Wp0, const float* __restrict__ ppb0,
    const u16* __restrict__ Wp1, const float* __restrict__ ppb1,
    const float* __restrict__ ppW2, const float* __restrict__ ppb2,
    float* __restrict__ out)
{
    __shared__ u16 sl0[16 * LSTR];
    __shared__ u16 sl1[16 * LSTR];
    int lane = threadIdx.x, m = lane & 15, quad = lane >> 4;
    int row16 = blockIdx.x * 16, row = row16 + m;
    f32x4 acc[8];

    // node update 2 -> sl0 (bf16, never touches global)
    zacc(acc);
    #pragma unroll
    for (int c = 0; c < 4; ++c)
        mm8(Wnp, c, a_from_f32(nenc + (size_t)row * H_ + c * 32 + quad * 8), acc, lane);
    #pragma unroll
    for (int c = 0; c < 4; ++c)
        mm8(Wnp, 4 + c, a_from_f32(agg + (size_t)row * H_ + c * 32 + quad * 8), acc, lane);
    #pragma unroll
    for (int nt = 0; nt < 8; ++nt) {
        int col = nt * 16 + m;
        float bv = npb[col];
        #pragma unroll
        for (int i = 0; i < 4; ++i) {
            int r = row16 + quad * 4 + i;
            float v = fmaxf(acc[nt][i] + bv + eff[(size_t)r * H_ + col], 0.f);
            sl0[(quad * 4 + i) * LSTR + col] = f2bf(v);
        }
    }

    // predictor layer 0: concat(nenc, nef2_slab)
    zacc(acc);
    #pragma unroll
    for (int c = 0; c < 4; ++c)
        mm8(Wp0, c, a_from_f32(nenc + (size_t)row * H_ + c * 32 + quad * 8), acc, lane);
    #pragma unroll
    for (int c = 0; c < 4; ++c)
        mm8(Wp0, 4 + c, a_from_slab(sl0, m, quad, c), acc, lane);
    epi_slab(sl1, acc, ppb0, quad, m);

    // predictor layer 1
    zacc(acc);
    #pragma unroll
    for (int c = 0; c < 4; ++c) mm8(Wp1, c, a_from_slab(sl1, m, quad, c), acc, lane);
    epi_slab(sl0, acc, ppb1, quad, m);

    // head: out[r,col] = p2[r,:] . ppW2[:,col] + ppb2[col]
    int r = lane & 15, col = lane >> 4;
    if (col < 3) {
        float s = 0.f;
        #pragma unroll 8
        for (int k = 0; k < 128; ++k)
            s += bf2f(sl0[r * LSTR + k]) * ppW2[k * 3 + col];
        out[(size_t)(row16 + r) * 3 + col] = s + ppb2[col];
    }
}

// ---------------------------------------------------------------------------
extern "C" void kernel_launch(void* const* d_in, const int* in_sizes, int n_in,
                              void* d_out, int out_size, void* d_ws, size_t ws_size,
                              hipStream_t stream) {
    (void)in_sizes; (void)n_in; (void)out_size; (void)ws_size;

    const float* x  = (const float*)d_in[0];
    const float* Rr = (const float*)d_in[1];
    const float* Rs = (const float*)d_in[2];
    // d_in[3] = pstep (==2, hard-coded)
    const float* neb0 = (const float*)d_in[5];
    const float* neb1 = (const float*)d_in[7];
    const float* neb2 = (const float*)d_in[9];
    const float* eeb0 = (const float*)d_in[11];
    const float* eeb1 = (const float*)d_in[13];
    const float* eeb2 = (const float*)d_in[15];
    const float* npb  = (const float*)d_in[17];
    const float* epb  = (const float*)d_in[19];
    const float* ppb0 = (const float*)d_in[21];
    const float* ppb1 = (const float*)d_in[23];
    const float* ppW2 = (const float*)d_in[24];
    const float* ppb2 = (const float*)d_in[25];

    char* ws = (char*)d_ws;
    size_t off = 0;
    auto alloc = [&](size_t bytes) -> char* {
        char* p = ws + off;
        off += (bytes + 255) & ~(size_t)255;
        return p;
    };

    // weight order: ne0,ne1,ne2, ee0,ee1,ee2, ep, np, pp0, pp1
    const int widx[10] = {4, 6, 8, 10, 12, 14, 18, 16, 20, 22};
    const int Kt[10]   = {32, 128, 128, 64, 128, 128, 384, 256, 256, 128};
    WPack P;
    u16* wf[10];
    for (int i = 0; i < 10; ++i) {
        wf[i] = (u16*)alloc((size_t)Kt[i] * 128 * 2);
        P.d[i] = { (const float*)d_in[widx[i]], wf[i] };
    }
    int*   recv = (int*)alloc(BE * 4);
    int*   send = (int*)alloc(BE * 4);
    float* nenc = (float*)alloc((size_t)BN * H_ * 4);
    float* nef1 = (float*)alloc((size_t)BN * H_ * 4);
    float* agg  = (float*)alloc((size_t)BN * H_ * 4);
    u16*   eenc = (u16*)alloc((size_t)BE * H_ * 2);

    // K1: prep + zero + extract
    k_prep<<<2048, 256, 0, stream>>>(P, agg, Rr, Rs, recv, send);

    // K2: encoders (edge tiles 0..2047, node tiles 2048..2303)
    k_enc<<<2304, 64, 0, stream>>>(x, recv, send,
                                   wf[0], neb0, wf[1], neb1, wf[2], neb2,
                                   wf[3], eeb0, wf[4], eeb1, wf[5], eeb2,
                                   nenc, eenc);

    // K3..K6: propagation + predictor
    k_eprop<<<2048, 64, 0, stream>>>(eenc, nenc, recv, send, wf[6], epb, agg);
    k_nprop<<<256, 64, 0, stream>>>(nenc, agg, nenc, wf[7], npb, nef1);
    k_eprop<<<2048, 64, 0, stream>>>(eenc, nef1, recv, send, wf[6], epb, agg);
    k_nprop_pred<<<256, 64, 0, stream>>>(nenc, agg, nef1,
                                         wf[7], npb, wf[8], ppb0, wf[9], ppb1,
                                         ppW2, ppb2, (float*)d_out);
}